// Round 2
// baseline (338.050 us; speedup 1.0000x reference)
//
#include <hip/hip_runtime.h>

// StainNormalization: out[d] = clip(exp(-(gamma[d] * sum_c(-ln(x_c+1e-6))*M[c][d] + beta[d])), 0, 1)
// Folded: out[d] = min(exp2(sum_c log2(x_c+1e-6) * (M[c][d]*gamma[d]) - beta[d]/ln2), 1)
//   (exp2 >= 0 always, so lower clamp is free)
// Memory-bound: 403 MB traffic -> ~64us floor at 6.3 TB/s.
// Each thread: 4 pixels = 12 floats = 3 float4 loads/stores (fully coalesced, 48B/lane span).
// HW transcendentals: __builtin_amdgcn_logf -> v_log_f32 (log2), __builtin_amdgcn_exp2f -> v_exp_f32.

__global__ __launch_bounds__(256) void stain_norm_kernel(
    const float* __restrict__ x,
    const float* __restrict__ Mp,     // 3x3 row-major M[c*3+d]
    const float* __restrict__ gp,     // gamma[3]
    const float* __restrict__ bp,     // beta[3]
    float* __restrict__ out,
    int npix, int nquads)
{
    int tid = blockIdx.x * blockDim.x + threadIdx.x;
    if (tid >= nquads) return;

    // Uniform parameter loads (broadcast, cached)
    const float g0 = gp[0], g1 = gp[1], g2 = gp[2];
    const float A00 = Mp[0] * g0, A01 = Mp[1] * g1, A02 = Mp[2] * g2;
    const float A10 = Mp[3] * g0, A11 = Mp[4] * g1, A12 = Mp[5] * g2;
    const float A20 = Mp[6] * g0, A21 = Mp[7] * g1, A22 = Mp[8] * g2;
    const float INV_LN2 = 1.4426950408889634f;
    const float c0 = -bp[0] * INV_LN2;
    const float c1 = -bp[1] * INV_LN2;
    const float c2 = -bp[2] * INV_LN2;
    const float EPS = 1e-6f;

    const int p = tid * 4;  // first pixel of this thread's quad
    if (p + 4 <= npix) {
        // fast path: 3 vectorized float4 loads = 4 pixels
        const float4* __restrict__ xv = reinterpret_cast<const float4*>(x) + (size_t)tid * 3;
        float4 v0 = xv[0];
        float4 v1 = xv[1];
        float4 v2 = xv[2];
        float f[12];
        *reinterpret_cast<float4*>(&f[0]) = v0;
        *reinterpret_cast<float4*>(&f[4]) = v1;
        *reinterpret_cast<float4*>(&f[8]) = v2;
        float o[12];
#pragma unroll
        for (int j = 0; j < 4; ++j) {
            const float l0 = __builtin_amdgcn_logf(f[3 * j + 0] + EPS);
            const float l1 = __builtin_amdgcn_logf(f[3 * j + 1] + EPS);
            const float l2 = __builtin_amdgcn_logf(f[3 * j + 2] + EPS);
            o[3 * j + 0] = fminf(__builtin_amdgcn_exp2f(fmaf(l0, A00, fmaf(l1, A10, fmaf(l2, A20, c0)))), 1.0f);
            o[3 * j + 1] = fminf(__builtin_amdgcn_exp2f(fmaf(l0, A01, fmaf(l1, A11, fmaf(l2, A21, c1)))), 1.0f);
            o[3 * j + 2] = fminf(__builtin_amdgcn_exp2f(fmaf(l0, A02, fmaf(l1, A12, fmaf(l2, A22, c2)))), 1.0f);
        }
        float4* __restrict__ ov = reinterpret_cast<float4*>(out) + (size_t)tid * 3;
        ov[0] = *reinterpret_cast<float4*>(&o[0]);
        ov[1] = *reinterpret_cast<float4*>(&o[4]);
        ov[2] = *reinterpret_cast<float4*>(&o[8]);
    } else {
        // tail: scalar per-pixel
        for (int q = p; q < npix; ++q) {
            const float l0 = __builtin_amdgcn_logf(x[3 * q + 0] + EPS);
            const float l1 = __builtin_amdgcn_logf(x[3 * q + 1] + EPS);
            const float l2 = __builtin_amdgcn_logf(x[3 * q + 2] + EPS);
            out[3 * q + 0] = fminf(__builtin_amdgcn_exp2f(fmaf(l0, A00, fmaf(l1, A10, fmaf(l2, A20, c0)))), 1.0f);
            out[3 * q + 1] = fminf(__builtin_amdgcn_exp2f(fmaf(l0, A01, fmaf(l1, A11, fmaf(l2, A21, c1)))), 1.0f);
            out[3 * q + 2] = fminf(__builtin_amdgcn_exp2f(fmaf(l0, A02, fmaf(l1, A12, fmaf(l2, A22, c2)))), 1.0f);
        }
    }
}

extern "C" void kernel_launch(void* const* d_in, const int* in_sizes, int n_in,
                              void* d_out, int out_size, void* d_ws, size_t ws_size,
                              hipStream_t stream) {
    const float* x     = (const float*)d_in[0];
    const float* M     = (const float*)d_in[1];
    const float* gamma = (const float*)d_in[2];
    const float* beta  = (const float*)d_in[3];
    float* out = (float*)d_out;

    const int n = in_sizes[0];        // total floats (B*H*W*3)
    const int npix = n / 3;           // pixels
    const int nquads = (npix + 3) / 4;
    const int block = 256;
    const int grid = (nquads + block - 1) / block;

    stain_norm_kernel<<<grid, block, 0, stream>>>(x, M, gamma, beta, out, npix, nquads);
}